// Round 1
// baseline (107.563 us; speedup 1.0000x reference)
//
#include <hip/hip_runtime.h>

#define NSTROKES 64
#define NSAMP    50
#define CANVAS   512
#define TPB      128   // threads per block; 4 px/thread -> one 512-px row per block

__global__ __launch_bounds__(TPB) void raster_kernel(
    const float* __restrict__ strokes,   // (64,4,2)
    const float* __restrict__ widths,    // (64,)
    const float* __restrict__ colors,    // (64,3)
    float* __restrict__ out)             // (1,3,512,512)
{
    __shared__ float2 spts[NSTROKES * NSAMP];   // sampled curve points (x,y), *512
    __shared__ float4 sbb [NSTROKES];           // bbox: minx,miny,maxx,maxy (*512)
    __shared__ float  swid[NSTROKES];
    __shared__ float4 scol[NSTROKES];           // r,g,b,pad

    const int tid = threadIdx.x;

    // ---- setup: sample bezier points into LDS (duplicated per block; ~2% cost)
    for (int k = tid; k < NSTROKES * NSAMP; k += TPB) {
        int s = k / NSAMP;
        int j = k - s * NSAMP;
        float t  = (float)j * (1.0f / (float)(NSAMP - 1));
        float u  = 1.0f - t;
        float b0 = u * u * u;
        float b1 = 3.0f * u * u * t;
        float b2 = 3.0f * u * t * t;
        float b3 = t * t * t;
        float4 a = ((const float4*)strokes)[s * 2];       // x0,y0,x1,y1
        float4 b = ((const float4*)strokes)[s * 2 + 1];   // x2,y2,x3,y3
        float px = (b0 * a.x + b1 * a.z + b2 * b.x + b3 * b.z) * (float)CANVAS;
        float py = (b0 * a.y + b1 * a.w + b2 * b.y + b3 * b.w) * (float)CANVAS;
        spts[k] = make_float2(px, py);
    }
    if (tid < NSTROKES) {
        float4 a = ((const float4*)strokes)[tid * 2];
        float4 b = ((const float4*)strokes)[tid * 2 + 1];
        float mnx = fminf(fminf(a.x, a.z), fminf(b.x, b.z)) * (float)CANVAS;
        float mny = fminf(fminf(a.y, a.w), fminf(b.y, b.w)) * (float)CANVAS;
        float mxx = fmaxf(fmaxf(a.x, a.z), fmaxf(b.x, b.z)) * (float)CANVAS;
        float mxy = fmaxf(fmaxf(a.y, a.w), fmaxf(b.y, b.w)) * (float)CANVAS;
        sbb [tid] = make_float4(mnx, mny, mxx, mxy);
        swid[tid] = widths[tid];
        scol[tid] = make_float4(colors[3*tid], colors[3*tid+1], colors[3*tid+2], 0.0f);
    }
    __syncthreads();

    // ---- main: each thread owns 4 consecutive pixels of row blockIdx.x
    const int   y   = blockIdx.x;
    const int   x0  = tid * 4;
    const float fy  = (float)y;
    const float fx0 = (float)x0;
    const float fx1 = fx0 + 1.0f, fx2 = fx0 + 2.0f, fx3 = fx0 + 3.0f;

    float cr0=1.f,cg0=1.f,cb0=1.f, cr1=1.f,cg1=1.f,cb1=1.f;
    float cr2=1.f,cg2=1.f,cb2=1.f, cr3=1.f,cg3=1.f,cb3=1.f;

    for (int s = 0; s < NSTROKES; ++s) {
        float4 bb = sbb[s];
        float  w  = swid[s];

        // conservative cull: curve lies inside control-point bbox; if the whole
        // wave's x-span is > w+10 away, alpha < sigmoid(-20) ~ 2e-9 -> skip.
        float ddx = fmaxf(fmaxf(bb.x - fx3, fx0 - bb.z), 0.0f);
        float ddy = fmaxf(fmaxf(bb.y - fy,  fy  - bb.w), 0.0f);
        float cut = w + 10.0f;
        bool  skip = (ddx*ddx + ddy*ddy) > cut*cut;
        if (__all(skip)) continue;

        float m0 = 1e30f, m1 = 1e30f, m2 = 1e30f, m3 = 1e30f;
        const float4* P4 = (const float4*)(spts + s * NSAMP);  // 25 x (2 points)
        #pragma unroll
        for (int j = 0; j < NSAMP / 2; ++j) {
            float4 q = P4[j];                 // broadcast LDS read, no conflicts
            float dy0 = fy - q.y; float t0 = dy0 * dy0;
            float dy1 = fy - q.w; float t1 = dy1 * dy1;
            { float da = fx0 - q.x, db = fx0 - q.z;
              m0 = fminf(fminf(fmaf(da,da,t0), fmaf(db,db,t1)), m0); }
            { float da = fx1 - q.x, db = fx1 - q.z;
              m1 = fminf(fminf(fmaf(da,da,t0), fmaf(db,db,t1)), m1); }
            { float da = fx2 - q.x, db = fx2 - q.z;
              m2 = fminf(fminf(fmaf(da,da,t0), fmaf(db,db,t1)), m2); }
            { float da = fx3 - q.x, db = fx3 - q.z;
              m3 = fminf(fminf(fmaf(da,da,t0), fmaf(db,db,t1)), m3); }
        }

        float4 col = scol[s];
        float a0 = __builtin_amdgcn_rcpf(1.0f + __expf(2.0f * (sqrtf(m0) - w)));
        float a1 = __builtin_amdgcn_rcpf(1.0f + __expf(2.0f * (sqrtf(m1) - w)));
        float a2 = __builtin_amdgcn_rcpf(1.0f + __expf(2.0f * (sqrtf(m2) - w)));
        float a3 = __builtin_amdgcn_rcpf(1.0f + __expf(2.0f * (sqrtf(m3) - w)));

        cr0 = fmaf(a0, col.x - cr0, cr0); cg0 = fmaf(a0, col.y - cg0, cg0); cb0 = fmaf(a0, col.z - cb0, cb0);
        cr1 = fmaf(a1, col.x - cr1, cr1); cg1 = fmaf(a1, col.y - cg1, cg1); cb1 = fmaf(a1, col.z - cb1, cb1);
        cr2 = fmaf(a2, col.x - cr2, cr2); cg2 = fmaf(a2, col.y - cg2, cg2); cb2 = fmaf(a2, col.z - cb2, cb2);
        cr3 = fmaf(a3, col.x - cr3, cr3); cg3 = fmaf(a3, col.y - cg3, cg3); cb3 = fmaf(a3, col.z - cb3, cb3);
    }

    const int HW = CANVAS * CANVAS;
    const int base = y * CANVAS + x0;
    ((float4*)(out + 0*HW + base))[0] = make_float4(cr0, cr1, cr2, cr3);
    ((float4*)(out + 1*HW + base))[0] = make_float4(cg0, cg1, cg2, cg3);
    ((float4*)(out + 2*HW + base))[0] = make_float4(cb0, cb1, cb2, cb3);
}

extern "C" void kernel_launch(void* const* d_in, const int* in_sizes, int n_in,
                              void* d_out, int out_size, void* d_ws, size_t ws_size,
                              hipStream_t stream) {
    const float* strokes = (const float*)d_in[0];   // (64,4,2) f32
    const float* widths  = (const float*)d_in[1];   // (64,)    f32
    const float* colors  = (const float*)d_in[2];   // (64,3)   f32
    // d_in[3] = canvas_size (int, ==512) — hardcoded
    float* out = (float*)d_out;                     // (1,3,512,512) f32

    raster_kernel<<<dim3(CANVAS), dim3(TPB), 0, stream>>>(strokes, widths, colors, out);
}

// Round 2
// 61.129 us; speedup vs baseline: 1.7596x; 1.7596x over previous
//
#include <hip/hip_runtime.h>

#define NSTROKES 64
#define NSAMP    50
#define CANVAS   512
#define HW       (CANVAS * CANVAS)
#define TPB      128   // 4 px/thread -> one 512-px row per block
#define NGROUPS  4
#define SPG      (NSTROKES / NGROUPS)   // strokes per group

// ---------------------------------------------------------------------------
// Kernel 1: per (row, stroke-group) block computes the group's affine map
//   c -> A*c + B   per pixel (A scalar, B rgb), where each stroke applies
//   c -> (1-a)*c + a*col.  A = prod(1-a_i), B via B = fmaf(a, col-B, B).
// Output planes in ws: [(g*4+0)=A, (g*4+1)=Br, (g*4+2)=Bg, (g*4+3)=Bb] * HW.
// ---------------------------------------------------------------------------
__global__ __launch_bounds__(TPB) void raster_group_kernel(
    const float* __restrict__ strokes,   // (64,4,2)
    const float* __restrict__ widths,    // (64,)
    const float* __restrict__ colors,    // (64,3)
    float* __restrict__ ws)              // NGROUPS*4*HW floats
{
    __shared__ float2 spts[SPG * NSAMP];
    __shared__ float4 sbb [SPG];
    __shared__ float  swid[SPG];
    __shared__ float4 scol[SPG];

    const int tid   = threadIdx.x;
    const int g     = blockIdx.y;
    const int sbase = g * SPG;

    for (int k = tid; k < SPG * NSAMP; k += TPB) {
        int s = k / NSAMP;
        int j = k - s * NSAMP;
        float t  = (float)j * (1.0f / (float)(NSAMP - 1));
        float u  = 1.0f - t;
        float b0 = u * u * u;
        float b1 = 3.0f * u * u * t;
        float b2 = 3.0f * u * t * t;
        float b3 = t * t * t;
        float4 a = ((const float4*)strokes)[(sbase + s) * 2];
        float4 b = ((const float4*)strokes)[(sbase + s) * 2 + 1];
        float px = (b0 * a.x + b1 * a.z + b2 * b.x + b3 * b.z) * (float)CANVAS;
        float py = (b0 * a.y + b1 * a.w + b2 * b.y + b3 * b.w) * (float)CANVAS;
        spts[k] = make_float2(px, py);
    }
    if (tid < SPG) {
        int s = sbase + tid;
        float4 a = ((const float4*)strokes)[s * 2];
        float4 b = ((const float4*)strokes)[s * 2 + 1];
        float mnx = fminf(fminf(a.x, a.z), fminf(b.x, b.z)) * (float)CANVAS;
        float mny = fminf(fminf(a.y, a.w), fminf(b.y, b.w)) * (float)CANVAS;
        float mxx = fmaxf(fmaxf(a.x, a.z), fmaxf(b.x, b.z)) * (float)CANVAS;
        float mxy = fmaxf(fmaxf(a.y, a.w), fmaxf(b.y, b.w)) * (float)CANVAS;
        sbb [tid] = make_float4(mnx, mny, mxx, mxy);
        swid[tid] = widths[s];
        scol[tid] = make_float4(colors[3*s], colors[3*s+1], colors[3*s+2], 0.0f);
    }
    __syncthreads();

    const int   y   = blockIdx.x;
    const int   x0  = tid * 4;
    const float fy  = (float)y;
    const float fx0 = (float)x0;
    const float fx1 = fx0 + 1.0f, fx2 = fx0 + 2.0f, fx3 = fx0 + 3.0f;

    float A0 = 1.f, A1 = 1.f, A2 = 1.f, A3 = 1.f;
    float br0=0.f,bg0=0.f,bb0=0.f, br1=0.f,bg1=0.f,bb1=0.f;
    float br2=0.f,bg2=0.f,bb2=0.f, br3=0.f,bg3=0.f,bb3=0.f;

    for (int s = 0; s < SPG; ++s) {
        float4 bb = sbb[s];
        float  w  = swid[s];

        // conservative cull: alpha < sigmoid(-20) ~ 2e-9 for the whole wave
        float ddx = fmaxf(fmaxf(bb.x - fx3, fx0 - bb.z), 0.0f);
        float ddy = fmaxf(fmaxf(bb.y - fy,  fy  - bb.w), 0.0f);
        float cut = w + 10.0f;
        bool  skip = (ddx*ddx + ddy*ddy) > cut*cut;
        if (__all(skip)) continue;

        float m0 = 1e30f, m1 = 1e30f, m2 = 1e30f, m3 = 1e30f;
        const float4* P4 = (const float4*)(spts + s * NSAMP);
        #pragma unroll
        for (int j = 0; j < NSAMP / 2; ++j) {
            float4 q = P4[j];                 // broadcast LDS read
            float dy0 = fy - q.y; float t0 = dy0 * dy0;
            float dy1 = fy - q.w; float t1 = dy1 * dy1;
            { float da = fx0 - q.x, db = fx0 - q.z;
              m0 = fminf(fminf(fmaf(da,da,t0), fmaf(db,db,t1)), m0); }
            { float da = fx1 - q.x, db = fx1 - q.z;
              m1 = fminf(fminf(fmaf(da,da,t0), fmaf(db,db,t1)), m1); }
            { float da = fx2 - q.x, db = fx2 - q.z;
              m2 = fminf(fminf(fmaf(da,da,t0), fmaf(db,db,t1)), m2); }
            { float da = fx3 - q.x, db = fx3 - q.z;
              m3 = fminf(fminf(fmaf(da,da,t0), fmaf(db,db,t1)), m3); }
        }

        float4 col = scol[s];
        float a0 = __builtin_amdgcn_rcpf(1.0f + __expf(2.0f * (sqrtf(m0) - w)));
        float a1 = __builtin_amdgcn_rcpf(1.0f + __expf(2.0f * (sqrtf(m1) - w)));
        float a2 = __builtin_amdgcn_rcpf(1.0f + __expf(2.0f * (sqrtf(m2) - w)));
        float a3 = __builtin_amdgcn_rcpf(1.0f + __expf(2.0f * (sqrtf(m3) - w)));

        A0 *= (1.0f - a0); A1 *= (1.0f - a1); A2 *= (1.0f - a2); A3 *= (1.0f - a3);
        br0 = fmaf(a0, col.x - br0, br0); bg0 = fmaf(a0, col.y - bg0, bg0); bb0 = fmaf(a0, col.z - bb0, bb0);
        br1 = fmaf(a1, col.x - br1, br1); bg1 = fmaf(a1, col.y - bg1, bg1); bb1 = fmaf(a1, col.z - bb1, bb1);
        br2 = fmaf(a2, col.x - br2, br2); bg2 = fmaf(a2, col.y - bg2, bg2); bb2 = fmaf(a2, col.z - bb2, bb2);
        br3 = fmaf(a3, col.x - br3, br3); bg3 = fmaf(a3, col.y - bg3, bg3); bb3 = fmaf(a3, col.z - bb3, bb3);
    }

    const int base = y * CANVAS + x0;
    float* wp = ws + (size_t)g * 4 * HW;
    ((float4*)(wp + 0*HW + base))[0] = make_float4(A0, A1, A2, A3);
    ((float4*)(wp + 1*HW + base))[0] = make_float4(br0, br1, br2, br3);
    ((float4*)(wp + 2*HW + base))[0] = make_float4(bg0, bg1, bg2, bg3);
    ((float4*)(wp + 3*HW + base))[0] = make_float4(bb0, bb1, bb2, bb3);
}

// ---------------------------------------------------------------------------
// Kernel 2: fold the NGROUPS affine maps (in order) onto the white canvas.
// ---------------------------------------------------------------------------
__global__ __launch_bounds__(256) void combine_kernel(
    const float* __restrict__ ws, float* __restrict__ out)
{
    const int t    = blockIdx.x * 256 + threadIdx.x;   // HW/4 threads
    const int base = t * 4;

    float4 cr = make_float4(1.f,1.f,1.f,1.f);
    float4 cg = make_float4(1.f,1.f,1.f,1.f);
    float4 cb = make_float4(1.f,1.f,1.f,1.f);

    #pragma unroll
    for (int g = 0; g < NGROUPS; ++g) {
        const float* wp = ws + (size_t)g * 4 * HW;
        float4 A  = ((const float4*)(wp + 0*HW + base))[0];
        float4 Br = ((const float4*)(wp + 1*HW + base))[0];
        float4 Bg = ((const float4*)(wp + 2*HW + base))[0];
        float4 Bb = ((const float4*)(wp + 3*HW + base))[0];
        cr.x = fmaf(A.x, cr.x, Br.x); cr.y = fmaf(A.y, cr.y, Br.y);
        cr.z = fmaf(A.z, cr.z, Br.z); cr.w = fmaf(A.w, cr.w, Br.w);
        cg.x = fmaf(A.x, cg.x, Bg.x); cg.y = fmaf(A.y, cg.y, Bg.y);
        cg.z = fmaf(A.z, cg.z, Bg.z); cg.w = fmaf(A.w, cg.w, Bg.w);
        cb.x = fmaf(A.x, cb.x, Bb.x); cb.y = fmaf(A.y, cb.y, Bb.y);
        cb.z = fmaf(A.z, cb.z, Bb.z); cb.w = fmaf(A.w, cb.w, Bb.w);
    }

    ((float4*)(out + 0*HW + base))[0] = cr;
    ((float4*)(out + 1*HW + base))[0] = cg;
    ((float4*)(out + 2*HW + base))[0] = cb;
}

// ---------------------------------------------------------------------------
// Fallback (ws too small): round-1 direct kernel, known-good.
// ---------------------------------------------------------------------------
__global__ __launch_bounds__(TPB) void raster_direct_kernel(
    const float* __restrict__ strokes, const float* __restrict__ widths,
    const float* __restrict__ colors, float* __restrict__ out)
{
    __shared__ float2 spts[NSTROKES * NSAMP];
    __shared__ float4 sbb [NSTROKES];
    __shared__ float  swid[NSTROKES];
    __shared__ float4 scol[NSTROKES];

    const int tid = threadIdx.x;
    for (int k = tid; k < NSTROKES * NSAMP; k += TPB) {
        int s = k / NSAMP;
        int j = k - s * NSAMP;
        float t  = (float)j * (1.0f / (float)(NSAMP - 1));
        float u  = 1.0f - t;
        float b0 = u*u*u, b1 = 3.f*u*u*t, b2 = 3.f*u*t*t, b3 = t*t*t;
        float4 a = ((const float4*)strokes)[s * 2];
        float4 b = ((const float4*)strokes)[s * 2 + 1];
        spts[k] = make_float2((b0*a.x + b1*a.z + b2*b.x + b3*b.z) * (float)CANVAS,
                              (b0*a.y + b1*a.w + b2*b.y + b3*b.w) * (float)CANVAS);
    }
    if (tid < NSTROKES) {
        float4 a = ((const float4*)strokes)[tid * 2];
        float4 b = ((const float4*)strokes)[tid * 2 + 1];
        sbb [tid] = make_float4(fminf(fminf(a.x,a.z),fminf(b.x,b.z)) * (float)CANVAS,
                                fminf(fminf(a.y,a.w),fminf(b.y,b.w)) * (float)CANVAS,
                                fmaxf(fmaxf(a.x,a.z),fmaxf(b.x,b.z)) * (float)CANVAS,
                                fmaxf(fmaxf(a.y,a.w),fmaxf(b.y,b.w)) * (float)CANVAS);
        swid[tid] = widths[tid];
        scol[tid] = make_float4(colors[3*tid], colors[3*tid+1], colors[3*tid+2], 0.0f);
    }
    __syncthreads();

    const int   y   = blockIdx.x;
    const int   x0  = tid * 4;
    const float fy  = (float)y;
    const float fx0 = (float)x0;
    const float fx1 = fx0+1.f, fx2 = fx0+2.f, fx3 = fx0+3.f;

    float cr0=1.f,cg0=1.f,cb0=1.f, cr1=1.f,cg1=1.f,cb1=1.f;
    float cr2=1.f,cg2=1.f,cb2=1.f, cr3=1.f,cg3=1.f,cb3=1.f;

    for (int s = 0; s < NSTROKES; ++s) {
        float4 bb = sbb[s];
        float  w  = swid[s];
        float ddx = fmaxf(fmaxf(bb.x - fx3, fx0 - bb.z), 0.0f);
        float ddy = fmaxf(fmaxf(bb.y - fy,  fy  - bb.w), 0.0f);
        float cut = w + 10.0f;
        if (__all((ddx*ddx + ddy*ddy) > cut*cut)) continue;

        float m0 = 1e30f, m1 = 1e30f, m2 = 1e30f, m3 = 1e30f;
        const float4* P4 = (const float4*)(spts + s * NSAMP);
        #pragma unroll
        for (int j = 0; j < NSAMP / 2; ++j) {
            float4 q = P4[j];
            float dy0 = fy - q.y; float t0 = dy0 * dy0;
            float dy1 = fy - q.w; float t1 = dy1 * dy1;
            { float da = fx0 - q.x, db = fx0 - q.z;
              m0 = fminf(fminf(fmaf(da,da,t0), fmaf(db,db,t1)), m0); }
            { float da = fx1 - q.x, db = fx1 - q.z;
              m1 = fminf(fminf(fmaf(da,da,t0), fmaf(db,db,t1)), m1); }
            { float da = fx2 - q.x, db = fx2 - q.z;
              m2 = fminf(fminf(fmaf(da,da,t0), fmaf(db,db,t1)), m2); }
            { float da = fx3 - q.x, db = fx3 - q.z;
              m3 = fminf(fminf(fmaf(da,da,t0), fmaf(db,db,t1)), m3); }
        }

        float4 col = scol[s];
        float a0 = __builtin_amdgcn_rcpf(1.0f + __expf(2.0f * (sqrtf(m0) - w)));
        float a1 = __builtin_amdgcn_rcpf(1.0f + __expf(2.0f * (sqrtf(m1) - w)));
        float a2 = __builtin_amdgcn_rcpf(1.0f + __expf(2.0f * (sqrtf(m2) - w)));
        float a3 = __builtin_amdgcn_rcpf(1.0f + __expf(2.0f * (sqrtf(m3) - w)));

        cr0 = fmaf(a0, col.x - cr0, cr0); cg0 = fmaf(a0, col.y - cg0, cg0); cb0 = fmaf(a0, col.z - cb0, cb0);
        cr1 = fmaf(a1, col.x - cr1, cr1); cg1 = fmaf(a1, col.y - cg1, cg1); cb1 = fmaf(a1, col.z - cb1, cb1);
        cr2 = fmaf(a2, col.x - cr2, cr2); cg2 = fmaf(a2, col.y - cg2, cg2); cb2 = fmaf(a2, col.z - cb2, cb2);
        cr3 = fmaf(a3, col.x - cr3, cr3); cg3 = fmaf(a3, col.y - cg3, cg3); cb3 = fmaf(a3, col.z - cb3, cb3);
    }

    const int base = y * CANVAS + x0;
    ((float4*)(out + 0*HW + base))[0] = make_float4(cr0, cr1, cr2, cr3);
    ((float4*)(out + 1*HW + base))[0] = make_float4(cg0, cg1, cg2, cg3);
    ((float4*)(out + 2*HW + base))[0] = make_float4(cb0, cb1, cb2, cb3);
}

extern "C" void kernel_launch(void* const* d_in, const int* in_sizes, int n_in,
                              void* d_out, int out_size, void* d_ws, size_t ws_size,
                              hipStream_t stream) {
    const float* strokes = (const float*)d_in[0];
    const float* widths  = (const float*)d_in[1];
    const float* colors  = (const float*)d_in[2];
    float* out = (float*)d_out;

    const size_t need = (size_t)NGROUPS * 4 * HW * sizeof(float);
    if (ws_size >= need) {
        raster_group_kernel<<<dim3(CANVAS, NGROUPS), dim3(TPB), 0, stream>>>(
            strokes, widths, colors, (float*)d_ws);
        combine_kernel<<<dim3(HW / 4 / 256), dim3(256), 0, stream>>>(
            (const float*)d_ws, out);
    } else {
        raster_direct_kernel<<<dim3(CANVAS), dim3(TPB), 0, stream>>>(
            strokes, widths, colors, out);
    }
}

// Round 3
// 31.178 us; speedup vs baseline: 3.4499x; 1.9606x over previous
//
#include <hip/hip_runtime.h>

#define NSTROKES 64
#define NSAMP    50
#define CANVAS   512
#define HW       (CANVAS * CANVAS)
#define TPB      128   // 4 px/thread -> one 512-px row per block
#define NGROUPS  4
#define SPG      (NSTROKES / NGROUPS)   // strokes per group
#define LSTRIDE  52                     // float2 slots per stroke list (16B-aligned rows)

// ---------------------------------------------------------------------------
// Kernel 1: per (row, stroke-group) block computes the group's affine map
//   c -> A*c + B  per pixel. NEW: per-row sample compaction — only curve
//   samples with |py - fy| <= w+10 can contribute alpha > 2e-9; append those
//   to an LDS list per stroke and run the min-loop over the short list.
// ---------------------------------------------------------------------------
__global__ __launch_bounds__(TPB) void raster_group_kernel(
    const float* __restrict__ strokes,   // (64,4,2)
    const float* __restrict__ widths,    // (64,)
    const float* __restrict__ colors,    // (64,3)
    float* __restrict__ ws)              // NGROUPS*4*HW floats
{
    __shared__ float            scoef[SPG][8];          // Horner coeffs *512: c0x..c3x, c0y..c3y
    __shared__ __align__(16) float2 slist[SPG * LSTRIDE];
    __shared__ int              scnt[SPG];
    __shared__ float4           sbb [SPG];
    __shared__ float            swid[SPG];
    __shared__ float4           scol[SPG];

    const int tid   = threadIdx.x;
    const int g     = blockIdx.y;
    const int sbase = g * SPG;
    const int y     = blockIdx.x;
    const float fy  = (float)y;

    // ---- stage 1: per-stroke constants (16 threads)
    if (tid < SPG) {
        int s = sbase + tid;
        float4 a = ((const float4*)strokes)[s * 2];       // p0x,p0y,p1x,p1y
        float4 b = ((const float4*)strokes)[s * 2 + 1];   // p2x,p2y,p3x,p3y
        const float S = (float)CANVAS;
        scoef[tid][0] = a.x * S;
        scoef[tid][1] = 3.0f * (a.z - a.x) * S;
        scoef[tid][2] = 3.0f * (b.x - 2.0f * a.z + a.x) * S;
        scoef[tid][3] = (b.z - 3.0f * b.x + 3.0f * a.z - a.x) * S;
        scoef[tid][4] = a.y * S;
        scoef[tid][5] = 3.0f * (a.w - a.y) * S;
        scoef[tid][6] = 3.0f * (b.y - 2.0f * a.w + a.y) * S;
        scoef[tid][7] = (b.w - 3.0f * b.y + 3.0f * a.w - a.y) * S;
        scnt[tid] = 0;
        sbb [tid] = make_float4(fminf(fminf(a.x, a.z), fminf(b.x, b.z)) * S,
                                fminf(fminf(a.y, a.w), fminf(b.y, b.w)) * S,
                                fmaxf(fmaxf(a.x, a.z), fmaxf(b.x, b.z)) * S,
                                fmaxf(fmaxf(a.y, a.w), fmaxf(b.y, b.w)) * S);
        swid[tid] = widths[s];
        scol[tid] = make_float4(colors[3*s], colors[3*s+1], colors[3*s+2], 0.0f);
    }
    __syncthreads();

    // ---- stage 2: sample curves, keep only samples within the row band
    for (int k = tid; k < SPG * NSAMP; k += TPB) {
        int s = k / NSAMP;
        int j = k - s * NSAMP;
        float t = (float)j * (1.0f / (float)(NSAMP - 1));
        const float* C = scoef[s];
        float px = fmaf(fmaf(fmaf(C[3], t, C[2]), t, C[1]), t, C[0]);
        float py = fmaf(fmaf(fmaf(C[7], t, C[6]), t, C[5]), t, C[4]);
        float cut = swid[s] + 10.0f;   // alpha <= sigmoid(-20) ~ 2e-9 beyond
        if (fabsf(py - fy) <= cut) {
            int idx = atomicAdd(&scnt[s], 1);
            slist[s * LSTRIDE + idx] = make_float2(px, py);
        }
    }
    __syncthreads();

    // ---- stage 3: per-pixel min-dist over compacted lists, affine blend
    const int   x0  = tid * 4;
    const float fx0 = (float)x0;
    const float fx1 = fx0 + 1.0f, fx2 = fx0 + 2.0f, fx3 = fx0 + 3.0f;

    float A0 = 1.f, A1 = 1.f, A2 = 1.f, A3 = 1.f;
    float br0=0.f,bg0=0.f,bb0=0.f, br1=0.f,bg1=0.f,bb1=0.f;
    float br2=0.f,bg2=0.f,bb2=0.f, br3=0.f,bg3=0.f,bb3=0.f;

    for (int s = 0; s < SPG; ++s) {
        const int kc = scnt[s];
        if (kc == 0) continue;               // whole row outside band

        float4 bb = sbb[s];
        float  w  = swid[s];
        float cut = w + 10.0f;

        // per-wave x-cull (y handled by compaction)
        float ddx = fmaxf(fmaxf(bb.x - fx3, fx0 - bb.z), 0.0f);
        if (__all(ddx > cut)) continue;

        float m0 = 1e30f, m1 = 1e30f, m2 = 1e30f, m3 = 1e30f;
        const float2* L = slist + s * LSTRIDE;

        int j = 0;
        for (; j + 2 <= kc; j += 2) {
            float4 q = *(const float4*)(L + j);   // 2 samples, broadcast read
            float dy0 = fy - q.y; float t0 = dy0 * dy0;
            float dy1 = fy - q.w; float t1 = dy1 * dy1;
            { float da = fx0 - q.x, db = fx0 - q.z;
              m0 = fminf(fminf(fmaf(da,da,t0), fmaf(db,db,t1)), m0); }
            { float da = fx1 - q.x, db = fx1 - q.z;
              m1 = fminf(fminf(fmaf(da,da,t0), fmaf(db,db,t1)), m1); }
            { float da = fx2 - q.x, db = fx2 - q.z;
              m2 = fminf(fminf(fmaf(da,da,t0), fmaf(db,db,t1)), m2); }
            { float da = fx3 - q.x, db = fx3 - q.z;
              m3 = fminf(fminf(fmaf(da,da,t0), fmaf(db,db,t1)), m3); }
        }
        if (j < kc) {
            float2 p = L[j];
            float dy = fy - p.y; float t0 = dy * dy;
            { float da = fx0 - p.x; m0 = fminf(fmaf(da,da,t0), m0); }
            { float da = fx1 - p.x; m1 = fminf(fmaf(da,da,t0), m1); }
            { float da = fx2 - p.x; m2 = fminf(fmaf(da,da,t0), m2); }
            { float da = fx3 - p.x; m3 = fminf(fmaf(da,da,t0), m3); }
        }

        float4 col = scol[s];
        float a0 = __builtin_amdgcn_rcpf(1.0f + __expf(2.0f * (sqrtf(m0) - w)));
        float a1 = __builtin_amdgcn_rcpf(1.0f + __expf(2.0f * (sqrtf(m1) - w)));
        float a2 = __builtin_amdgcn_rcpf(1.0f + __expf(2.0f * (sqrtf(m2) - w)));
        float a3 = __builtin_amdgcn_rcpf(1.0f + __expf(2.0f * (sqrtf(m3) - w)));

        A0 *= (1.0f - a0); A1 *= (1.0f - a1); A2 *= (1.0f - a2); A3 *= (1.0f - a3);
        br0 = fmaf(a0, col.x - br0, br0); bg0 = fmaf(a0, col.y - bg0, bg0); bb0 = fmaf(a0, col.z - bb0, bb0);
        br1 = fmaf(a1, col.x - br1, br1); bg1 = fmaf(a1, col.y - bg1, bg1); bb1 = fmaf(a1, col.z - bb1, bb1);
        br2 = fmaf(a2, col.x - br2, br2); bg2 = fmaf(a2, col.y - bg2, bg2); bb2 = fmaf(a2, col.z - bb2, bb2);
        br3 = fmaf(a3, col.x - br3, br3); bg3 = fmaf(a3, col.y - bg3, bg3); bb3 = fmaf(a3, col.z - bb3, bb3);
    }

    const int base = y * CANVAS + x0;
    float* wp = ws + (size_t)g * 4 * HW;
    ((float4*)(wp + 0*HW + base))[0] = make_float4(A0, A1, A2, A3);
    ((float4*)(wp + 1*HW + base))[0] = make_float4(br0, br1, br2, br3);
    ((float4*)(wp + 2*HW + base))[0] = make_float4(bg0, bg1, bg2, bg3);
    ((float4*)(wp + 3*HW + base))[0] = make_float4(bb0, bb1, bb2, bb3);
}

// ---------------------------------------------------------------------------
// Kernel 2: fold the NGROUPS affine maps (in order) onto the white canvas.
// ---------------------------------------------------------------------------
__global__ __launch_bounds__(256) void combine_kernel(
    const float* __restrict__ ws, float* __restrict__ out)
{
    const int t    = blockIdx.x * 256 + threadIdx.x;   // HW/4 threads
    const int base = t * 4;

    float4 cr = make_float4(1.f,1.f,1.f,1.f);
    float4 cg = make_float4(1.f,1.f,1.f,1.f);
    float4 cb = make_float4(1.f,1.f,1.f,1.f);

    #pragma unroll
    for (int g = 0; g < NGROUPS; ++g) {
        const float* wp = ws + (size_t)g * 4 * HW;
        float4 A  = ((const float4*)(wp + 0*HW + base))[0];
        float4 Br = ((const float4*)(wp + 1*HW + base))[0];
        float4 Bg = ((const float4*)(wp + 2*HW + base))[0];
        float4 Bb = ((const float4*)(wp + 3*HW + base))[0];
        cr.x = fmaf(A.x, cr.x, Br.x); cr.y = fmaf(A.y, cr.y, Br.y);
        cr.z = fmaf(A.z, cr.z, Br.z); cr.w = fmaf(A.w, cr.w, Br.w);
        cg.x = fmaf(A.x, cg.x, Bg.x); cg.y = fmaf(A.y, cg.y, Bg.y);
        cg.z = fmaf(A.z, cg.z, Bg.z); cg.w = fmaf(A.w, cg.w, Bg.w);
        cb.x = fmaf(A.x, cb.x, Bb.x); cb.y = fmaf(A.y, cb.y, Bb.y);
        cb.z = fmaf(A.z, cb.z, Bb.z); cb.w = fmaf(A.w, cb.w, Bb.w);
    }

    ((float4*)(out + 0*HW + base))[0] = cr;
    ((float4*)(out + 1*HW + base))[0] = cg;
    ((float4*)(out + 2*HW + base))[0] = cb;
}

// ---------------------------------------------------------------------------
// Fallback (ws too small): round-1 direct kernel, known-good.
// ---------------------------------------------------------------------------
__global__ __launch_bounds__(TPB) void raster_direct_kernel(
    const float* __restrict__ strokes, const float* __restrict__ widths,
    const float* __restrict__ colors, float* __restrict__ out)
{
    __shared__ float2 spts[NSTROKES * NSAMP];
    __shared__ float4 sbb [NSTROKES];
    __shared__ float  swid[NSTROKES];
    __shared__ float4 scol[NSTROKES];

    const int tid = threadIdx.x;
    for (int k = tid; k < NSTROKES * NSAMP; k += TPB) {
        int s = k / NSAMP;
        int j = k - s * NSAMP;
        float t  = (float)j * (1.0f / (float)(NSAMP - 1));
        float u  = 1.0f - t;
        float b0 = u*u*u, b1 = 3.f*u*u*t, b2 = 3.f*u*t*t, b3 = t*t*t;
        float4 a = ((const float4*)strokes)[s * 2];
        float4 b = ((const float4*)strokes)[s * 2 + 1];
        spts[k] = make_float2((b0*a.x + b1*a.z + b2*b.x + b3*b.z) * (float)CANVAS,
                              (b0*a.y + b1*a.w + b2*b.y + b3*b.w) * (float)CANVAS);
    }
    if (tid < NSTROKES) {
        float4 a = ((const float4*)strokes)[tid * 2];
        float4 b = ((const float4*)strokes)[tid * 2 + 1];
        sbb [tid] = make_float4(fminf(fminf(a.x,a.z),fminf(b.x,b.z)) * (float)CANVAS,
                                fminf(fminf(a.y,a.w),fminf(b.y,b.w)) * (float)CANVAS,
                                fmaxf(fmaxf(a.x,a.z),fmaxf(b.x,b.z)) * (float)CANVAS,
                                fmaxf(fmaxf(a.y,a.w),fmaxf(b.y,b.w)) * (float)CANVAS);
        swid[tid] = widths[tid];
        scol[tid] = make_float4(colors[3*tid], colors[3*tid+1], colors[3*tid+2], 0.0f);
    }
    __syncthreads();

    const int   y   = blockIdx.x;
    const int   x0  = tid * 4;
    const float fy  = (float)y;
    const float fx0 = (float)x0;
    const float fx1 = fx0+1.f, fx2 = fx0+2.f, fx3 = fx0+3.f;

    float cr0=1.f,cg0=1.f,cb0=1.f, cr1=1.f,cg1=1.f,cb1=1.f;
    float cr2=1.f,cg2=1.f,cb2=1.f, cr3=1.f,cg3=1.f,cb3=1.f;

    for (int s = 0; s < NSTROKES; ++s) {
        float4 bb = sbb[s];
        float  w  = swid[s];
        float ddx = fmaxf(fmaxf(bb.x - fx3, fx0 - bb.z), 0.0f);
        float ddy = fmaxf(fmaxf(bb.y - fy,  fy  - bb.w), 0.0f);
        float cut = w + 10.0f;
        if (__all((ddx*ddx + ddy*ddy) > cut*cut)) continue;

        float m0 = 1e30f, m1 = 1e30f, m2 = 1e30f, m3 = 1e30f;
        const float4* P4 = (const float4*)(spts + s * NSAMP);
        #pragma unroll
        for (int j = 0; j < NSAMP / 2; ++j) {
            float4 q = P4[j];
            float dy0 = fy - q.y; float t0 = dy0 * dy0;
            float dy1 = fy - q.w; float t1 = dy1 * dy1;
            { float da = fx0 - q.x, db = fx0 - q.z;
              m0 = fminf(fminf(fmaf(da,da,t0), fmaf(db,db,t1)), m0); }
            { float da = fx1 - q.x, db = fx1 - q.z;
              m1 = fminf(fminf(fmaf(da,da,t0), fmaf(db,db,t1)), m1); }
            { float da = fx2 - q.x, db = fx2 - q.z;
              m2 = fminf(fminf(fmaf(da,da,t0), fmaf(db,db,t1)), m2); }
            { float da = fx3 - q.x, db = fx3 - q.z;
              m3 = fminf(fminf(fmaf(da,da,t0), fmaf(db,db,t1)), m3); }
        }

        float4 col = scol[s];
        float a0 = __builtin_amdgcn_rcpf(1.0f + __expf(2.0f * (sqrtf(m0) - w)));
        float a1 = __builtin_amdgcn_rcpf(1.0f + __expf(2.0f * (sqrtf(m1) - w)));
        float a2 = __builtin_amdgcn_rcpf(1.0f + __expf(2.0f * (sqrtf(m2) - w)));
        float a3 = __builtin_amdgcn_rcpf(1.0f + __expf(2.0f * (sqrtf(m3) - w)));

        cr0 = fmaf(a0, col.x - cr0, cr0); cg0 = fmaf(a0, col.y - cg0, cg0); cb0 = fmaf(a0, col.z - cb0, cb0);
        cr1 = fmaf(a1, col.x - cr1, cr1); cg1 = fmaf(a1, col.y - cg1, cg1); cb1 = fmaf(a1, col.z - cb1, cb1);
        cr2 = fmaf(a2, col.x - cr2, cr2); cg2 = fmaf(a2, col.y - cg2, cg2); cb2 = fmaf(a2, col.z - cb2, cb2);
        cr3 = fmaf(a3, col.x - cr3, cr3); cg3 = fmaf(a3, col.y - cg3, cg3); cb3 = fmaf(a3, col.z - cb3, cb3);
    }

    const int base = y * CANVAS + x0;
    ((float4*)(out + 0*HW + base))[0] = make_float4(cr0, cr1, cr2, cr3);
    ((float4*)(out + 1*HW + base))[0] = make_float4(cg0, cg1, cg2, cg3);
    ((float4*)(out + 2*HW + base))[0] = make_float4(cb0, cb1, cb2, cb3);
}

extern "C" void kernel_launch(void* const* d_in, const int* in_sizes, int n_in,
                              void* d_out, int out_size, void* d_ws, size_t ws_size,
                              hipStream_t stream) {
    const float* strokes = (const float*)d_in[0];
    const float* widths  = (const float*)d_in[1];
    const float* colors  = (const float*)d_in[2];
    float* out = (float*)d_out;

    const size_t need = (size_t)NGROUPS * 4 * HW * sizeof(float);
    if (ws_size >= need) {
        raster_group_kernel<<<dim3(CANVAS, NGROUPS), dim3(TPB), 0, stream>>>(
            strokes, widths, colors, (float*)d_ws);
        combine_kernel<<<dim3(HW / 4 / 256), dim3(256), 0, stream>>>(
            (const float*)d_ws, out);
    } else {
        raster_direct_kernel<<<dim3(CANVAS), dim3(TPB), 0, stream>>>(
            strokes, widths, colors, out);
    }
}

// Round 4
// 27.599 us; speedup vs baseline: 3.8973x; 1.1297x over previous
//
#include <hip/hip_runtime.h>

#define NSTROKES 64
#define NSAMP    50
#define CANVAS   512
#define HW       (CANVAS * CANVAS)
#define TPB      256   // 2 px/thread -> one 512-px row per block, 4 waves/block
#define NGROUPS  4
#define SPG      (NSTROKES / NGROUPS)   // strokes per group
#define LSTRIDE  52                     // float2 slots per stroke list (16B-aligned rows)

// ---------------------------------------------------------------------------
// Kernel 1: per (row, stroke-group) block computes the group's affine map
//   c -> A*c + B per pixel. Per-row sample compaction (|py-fy| <= w+10) into
//   LDS lists + exact x-range of kept samples for tight wave-level culls.
// ---------------------------------------------------------------------------
__global__ __launch_bounds__(TPB) void raster_group_kernel(
    const float* __restrict__ strokes,   // (64,4,2)
    const float* __restrict__ widths,    // (64,)
    const float* __restrict__ colors,    // (64,3)
    float* __restrict__ ws)              // NGROUPS*4*HW floats
{
    __shared__ float            scoef[SPG][8];   // Horner coeffs *512
    __shared__ __align__(16) float2 slist[SPG * LSTRIDE];
    __shared__ int              scnt[SPG];
    __shared__ int              sxmin[SPG];      // float bits of min px (kept samples)
    __shared__ int              sxmax[SPG];      // float bits of max px
    __shared__ float            swid[SPG];
    __shared__ float4           scol[SPG];

    const int tid   = threadIdx.x;
    const int g     = blockIdx.y;
    const int sbase = g * SPG;
    const int y     = blockIdx.x;
    const float fy  = (float)y;

    // ---- stage 1: per-stroke constants
    if (tid < SPG) {
        int s = sbase + tid;
        float4 a = ((const float4*)strokes)[s * 2];       // p0x,p0y,p1x,p1y
        float4 b = ((const float4*)strokes)[s * 2 + 1];   // p2x,p2y,p3x,p3y
        const float S = (float)CANVAS;
        scoef[tid][0] = a.x * S;
        scoef[tid][1] = 3.0f * (a.z - a.x) * S;
        scoef[tid][2] = 3.0f * (b.x - 2.0f * a.z + a.x) * S;
        scoef[tid][3] = (b.z - 3.0f * b.x + 3.0f * a.z - a.x) * S;
        scoef[tid][4] = a.y * S;
        scoef[tid][5] = 3.0f * (a.w - a.y) * S;
        scoef[tid][6] = 3.0f * (b.y - 2.0f * a.w + a.y) * S;
        scoef[tid][7] = (b.w - 3.0f * b.y + 3.0f * a.w - a.y) * S;
        scnt [tid] = 0;
        sxmin[tid] = 0x7f7fffff;   // FLT_MAX bits (px >= 0 so int-compare == float-compare)
        sxmax[tid] = 0;            // 0.0f bits
        swid [tid] = widths[s];
        scol [tid] = make_float4(colors[3*s], colors[3*s+1], colors[3*s+2], 0.0f);
    }
    __syncthreads();

    // ---- stage 2: sample curves; keep samples within the row band; track x-range
    for (int k = tid; k < SPG * NSAMP; k += TPB) {
        int s = k / NSAMP;
        int j = k - s * NSAMP;
        float t = (float)j * (1.0f / (float)(NSAMP - 1));
        const float* C = scoef[s];
        float px = fmaf(fmaf(fmaf(C[3], t, C[2]), t, C[1]), t, C[0]);
        float py = fmaf(fmaf(fmaf(C[7], t, C[6]), t, C[5]), t, C[4]);
        float cut = swid[s] + 10.0f;   // alpha <= sigmoid(-20) ~ 2e-9 beyond
        if (fabsf(py - fy) <= cut) {
            int idx = atomicAdd(&scnt[s], 1);
            slist[s * LSTRIDE + idx] = make_float2(px, py);
            atomicMin(&sxmin[s], __float_as_int(px));
            atomicMax(&sxmax[s], __float_as_int(px));
        }
    }
    __syncthreads();

    // ---- stage 3: per-pixel min-dist over compacted lists, affine blend
    const int   x0  = tid * 2;
    const float fx0 = (float)x0;
    const float fx1 = fx0 + 1.0f;

    float A0 = 1.f, A1 = 1.f;
    float br0=0.f,bg0=0.f,bb0=0.f, br1=0.f,bg1=0.f,bb1=0.f;

    for (int s = 0; s < SPG; ++s) {
        const int kc = scnt[s];
        if (kc == 0) continue;               // whole row outside band

        float w   = swid[s];
        float cut = w + 10.0f;
        float xmn = __int_as_float(sxmin[s]);
        float xmx = __int_as_float(sxmax[s]);

        // exact x-range cull over kept samples (y handled by compaction)
        float ddx = fmaxf(fmaxf(xmn - fx1, fx0 - xmx), 0.0f);
        if (__all(ddx > cut)) continue;

        float m0 = 1e30f, m1 = 1e30f;
        const float2* L = slist + s * LSTRIDE;

        int j = 0;
        for (; j + 2 <= kc; j += 2) {
            float4 q = *(const float4*)(L + j);   // 2 samples, broadcast read
            float dy0 = fy - q.y; float t0 = dy0 * dy0;
            float dy1 = fy - q.w; float t1 = dy1 * dy1;
            { float da = fx0 - q.x, db = fx0 - q.z;
              m0 = fminf(fminf(fmaf(da,da,t0), fmaf(db,db,t1)), m0); }
            { float da = fx1 - q.x, db = fx1 - q.z;
              m1 = fminf(fminf(fmaf(da,da,t0), fmaf(db,db,t1)), m1); }
        }
        if (j < kc) {
            float2 p = L[j];
            float dy = fy - p.y; float t0 = dy * dy;
            { float da = fx0 - p.x; m0 = fminf(fmaf(da,da,t0), m0); }
            { float da = fx1 - p.x; m1 = fminf(fmaf(da,da,t0), m1); }
        }

        float4 col = scol[s];
        float a0 = __builtin_amdgcn_rcpf(1.0f + __expf(2.0f * (sqrtf(m0) - w)));
        float a1 = __builtin_amdgcn_rcpf(1.0f + __expf(2.0f * (sqrtf(m1) - w)));

        A0 *= (1.0f - a0); A1 *= (1.0f - a1);
        br0 = fmaf(a0, col.x - br0, br0); bg0 = fmaf(a0, col.y - bg0, bg0); bb0 = fmaf(a0, col.z - bb0, bb0);
        br1 = fmaf(a1, col.x - br1, br1); bg1 = fmaf(a1, col.y - bg1, bg1); bb1 = fmaf(a1, col.z - bb1, bb1);
    }

    const int base = y * CANVAS + x0;
    float* wp = ws + (size_t)g * 4 * HW;
    ((float2*)(wp + 0*HW + base))[0] = make_float2(A0, A1);
    ((float2*)(wp + 1*HW + base))[0] = make_float2(br0, br1);
    ((float2*)(wp + 2*HW + base))[0] = make_float2(bg0, bg1);
    ((float2*)(wp + 3*HW + base))[0] = make_float2(bb0, bb1);
}

// ---------------------------------------------------------------------------
// Kernel 2: fold the NGROUPS affine maps (in order) onto the white canvas.
// ---------------------------------------------------------------------------
__global__ __launch_bounds__(256) void combine_kernel(
    const float* __restrict__ ws, float* __restrict__ out)
{
    const int t    = blockIdx.x * 256 + threadIdx.x;   // HW/4 threads
    const int base = t * 4;

    float4 cr = make_float4(1.f,1.f,1.f,1.f);
    float4 cg = make_float4(1.f,1.f,1.f,1.f);
    float4 cb = make_float4(1.f,1.f,1.f,1.f);

    #pragma unroll
    for (int g = 0; g < NGROUPS; ++g) {
        const float* wp = ws + (size_t)g * 4 * HW;
        float4 A  = ((const float4*)(wp + 0*HW + base))[0];
        float4 Br = ((const float4*)(wp + 1*HW + base))[0];
        float4 Bg = ((const float4*)(wp + 2*HW + base))[0];
        float4 Bb = ((const float4*)(wp + 3*HW + base))[0];
        cr.x = fmaf(A.x, cr.x, Br.x); cr.y = fmaf(A.y, cr.y, Br.y);
        cr.z = fmaf(A.z, cr.z, Br.z); cr.w = fmaf(A.w, cr.w, Br.w);
        cg.x = fmaf(A.x, cg.x, Bg.x); cg.y = fmaf(A.y, cg.y, Bg.y);
        cg.z = fmaf(A.z, cg.z, Bg.z); cg.w = fmaf(A.w, cg.w, Bg.w);
        cb.x = fmaf(A.x, cb.x, Bb.x); cb.y = fmaf(A.y, cb.y, Bb.y);
        cb.z = fmaf(A.z, cb.z, Bb.z); cb.w = fmaf(A.w, cb.w, Bb.w);
    }

    ((float4*)(out + 0*HW + base))[0] = cr;
    ((float4*)(out + 1*HW + base))[0] = cg;
    ((float4*)(out + 2*HW + base))[0] = cb;
}

// ---------------------------------------------------------------------------
// Fallback (ws too small): round-1 direct kernel, known-good.
// ---------------------------------------------------------------------------
__global__ __launch_bounds__(128) void raster_direct_kernel(
    const float* __restrict__ strokes, const float* __restrict__ widths,
    const float* __restrict__ colors, float* __restrict__ out)
{
    __shared__ float2 spts[NSTROKES * NSAMP];
    __shared__ float4 sbb [NSTROKES];
    __shared__ float  swid[NSTROKES];
    __shared__ float4 scol[NSTROKES];

    const int tid = threadIdx.x;
    for (int k = tid; k < NSTROKES * NSAMP; k += 128) {
        int s = k / NSAMP;
        int j = k - s * NSAMP;
        float t  = (float)j * (1.0f / (float)(NSAMP - 1));
        float u  = 1.0f - t;
        float b0 = u*u*u, b1 = 3.f*u*u*t, b2 = 3.f*u*t*t, b3 = t*t*t;
        float4 a = ((const float4*)strokes)[s * 2];
        float4 b = ((const float4*)strokes)[s * 2 + 1];
        spts[k] = make_float2((b0*a.x + b1*a.z + b2*b.x + b3*b.z) * (float)CANVAS,
                              (b0*a.y + b1*a.w + b2*b.y + b3*b.w) * (float)CANVAS);
    }
    if (tid < NSTROKES) {
        float4 a = ((const float4*)strokes)[tid * 2];
        float4 b = ((const float4*)strokes)[tid * 2 + 1];
        sbb [tid] = make_float4(fminf(fminf(a.x,a.z),fminf(b.x,b.z)) * (float)CANVAS,
                                fminf(fminf(a.y,a.w),fminf(b.y,b.w)) * (float)CANVAS,
                                fmaxf(fmaxf(a.x,a.z),fmaxf(b.x,b.z)) * (float)CANVAS,
                                fmaxf(fmaxf(a.y,a.w),fmaxf(b.y,b.w)) * (float)CANVAS);
        swid[tid] = widths[tid];
        scol[tid] = make_float4(colors[3*tid], colors[3*tid+1], colors[3*tid+2], 0.0f);
    }
    __syncthreads();

    const int   y   = blockIdx.x;
    const int   x0  = tid * 4;
    const float fy  = (float)y;
    const float fx0 = (float)x0;
    const float fx1 = fx0+1.f, fx2 = fx0+2.f, fx3 = fx0+3.f;

    float cr0=1.f,cg0=1.f,cb0=1.f, cr1=1.f,cg1=1.f,cb1=1.f;
    float cr2=1.f,cg2=1.f,cb2=1.f, cr3=1.f,cg3=1.f,cb3=1.f;

    for (int s = 0; s < NSTROKES; ++s) {
        float4 bb = sbb[s];
        float  w  = swid[s];
        float ddx = fmaxf(fmaxf(bb.x - fx3, fx0 - bb.z), 0.0f);
        float ddy = fmaxf(fmaxf(bb.y - fy,  fy  - bb.w), 0.0f);
        float cut = w + 10.0f;
        if (__all((ddx*ddx + ddy*ddy) > cut*cut)) continue;

        float m0 = 1e30f, m1 = 1e30f, m2 = 1e30f, m3 = 1e30f;
        const float4* P4 = (const float4*)(spts + s * NSAMP);
        #pragma unroll
        for (int j = 0; j < NSAMP / 2; ++j) {
            float4 q = P4[j];
            float dy0 = fy - q.y; float t0 = dy0 * dy0;
            float dy1 = fy - q.w; float t1 = dy1 * dy1;
            { float da = fx0 - q.x, db = fx0 - q.z;
              m0 = fminf(fminf(fmaf(da,da,t0), fmaf(db,db,t1)), m0); }
            { float da = fx1 - q.x, db = fx1 - q.z;
              m1 = fminf(fminf(fmaf(da,da,t0), fmaf(db,db,t1)), m1); }
            { float da = fx2 - q.x, db = fx2 - q.z;
              m2 = fminf(fminf(fmaf(da,da,t0), fmaf(db,db,t1)), m2); }
            { float da = fx3 - q.x, db = fx3 - q.z;
              m3 = fminf(fminf(fmaf(da,da,t0), fmaf(db,db,t1)), m3); }
        }

        float4 col = scol[s];
        float a0 = __builtin_amdgcn_rcpf(1.0f + __expf(2.0f * (sqrtf(m0) - w)));
        float a1 = __builtin_amdgcn_rcpf(1.0f + __expf(2.0f * (sqrtf(m1) - w)));
        float a2 = __builtin_amdgcn_rcpf(1.0f + __expf(2.0f * (sqrtf(m2) - w)));
        float a3 = __builtin_amdgcn_rcpf(1.0f + __expf(2.0f * (sqrtf(m3) - w)));

        cr0 = fmaf(a0, col.x - cr0, cr0); cg0 = fmaf(a0, col.y - cg0, cg0); cb0 = fmaf(a0, col.z - cb0, cb0);
        cr1 = fmaf(a1, col.x - cr1, cr1); cg1 = fmaf(a1, col.y - cg1, cg1); cb1 = fmaf(a1, col.z - cb1, cb1);
        cr2 = fmaf(a2, col.x - cr2, cr2); cg2 = fmaf(a2, col.y - cg2, cg2); cb2 = fmaf(a2, col.z - cb2, cb2);
        cr3 = fmaf(a3, col.x - cr3, cr3); cg3 = fmaf(a3, col.y - cg3, cg3); cb3 = fmaf(a3, col.z - cb3, cb3);
    }

    const int base = y * CANVAS + x0;
    ((float4*)(out + 0*HW + base))[0] = make_float4(cr0, cr1, cr2, cr3);
    ((float4*)(out + 1*HW + base))[0] = make_float4(cg0, cg1, cg2, cg3);
    ((float4*)(out + 2*HW + base))[0] = make_float4(cb0, cb1, cb2, cb3);
}

extern "C" void kernel_launch(void* const* d_in, const int* in_sizes, int n_in,
                              void* d_out, int out_size, void* d_ws, size_t ws_size,
                              hipStream_t stream) {
    const float* strokes = (const float*)d_in[0];
    const float* widths  = (const float*)d_in[1];
    const float* colors  = (const float*)d_in[2];
    float* out = (float*)d_out;

    const size_t need = (size_t)NGROUPS * 4 * HW * sizeof(float);
    if (ws_size >= need) {
        raster_group_kernel<<<dim3(CANVAS, NGROUPS), dim3(TPB), 0, stream>>>(
            strokes, widths, colors, (float*)d_ws);
        combine_kernel<<<dim3(HW / 4 / 256), dim3(256), 0, stream>>>(
            (const float*)d_ws, out);
    } else {
        raster_direct_kernel<<<dim3(CANVAS), dim3(128), 0, stream>>>(
            strokes, widths, colors, out);
    }
}